// Round 3
// baseline (573.982 us; speedup 1.0000x reference)
//
#include <hip/hip_runtime.h>

#define IN_CH   128
#define D_OUT   128   // OUT_CH*HEADS
#define HEADS   4
#define N_TYPES 4
#define N_CONF  5

// ---------------------------------------------------------------------------
// Kernel A: xt[t][n][d] = sum_i x[n][i] * W[t][i][d]
//           for t==0 additionally out[n][d] = xt[0][n][d] + bias[d]
// float4 LDS reads: per 4-i step 12x ds_read_b128 + 128 FMA -> VALU-bound.
// ---------------------------------------------------------------------------
__global__ __launch_bounds__(256) void k_linear(const float* __restrict__ x,
                                                const float* __restrict__ W,
                                                const float* __restrict__ bias,
                                                float* __restrict__ xt,
                                                float* __restrict__ out,
                                                int N, int nblocks) {
    __shared__ __align__(16) float Xs[64 * 132];   // 64 nodes x 128, stride 132
    __shared__ __align__(16) float Ws[32 * 128];   // 32-i chunk of W[t]

    const int t     = blockIdx.x / nblocks;
    const int nbase = (blockIdx.x % nblocks) * 64;
    const int tid   = threadIdx.x;

    for (int f = tid; f < 2048; f += 256) {
        const int n  = f >> 5;
        const int i4 = (f & 31) * 4;
        float4 v = make_float4(0.f, 0.f, 0.f, 0.f);
        const int ng = nbase + n;
        if (ng < N) v = *(const float4*)(x + (size_t)ng * IN_CH + i4);
        *(float4*)(Xs + n * 132 + i4) = v;
    }

    const int tx = tid & 31;   // d-group: d = 4*tx..4*tx+3
    const int ty = tid >> 5;   // node-group: nodes ty*8 .. ty*8+7

    float4 acc[8];
#pragma unroll
    for (int j = 0; j < 8; j++) acc[j] = make_float4(0.f, 0.f, 0.f, 0.f);

    const float* Wt = W + (size_t)t * IN_CH * D_OUT;

    for (int ib = 0; ib < 4; ib++) {
        __syncthreads();
        for (int f = tid; f < 1024; f += 256) {
            *(float4*)(Ws + f * 4) = *(const float4*)(Wt + ib * 32 * 128 + f * 4);
        }
        __syncthreads();
#pragma unroll
        for (int ii4 = 0; ii4 < 8; ii4++) {
            float4 w0 = *(const float4*)(Ws + (ii4 * 4 + 0) * 128 + tx * 4);
            float4 w1 = *(const float4*)(Ws + (ii4 * 4 + 1) * 128 + tx * 4);
            float4 w2 = *(const float4*)(Ws + (ii4 * 4 + 2) * 128 + tx * 4);
            float4 w3 = *(const float4*)(Ws + (ii4 * 4 + 3) * 128 + tx * 4);
#pragma unroll
            for (int j = 0; j < 8; j++) {
                const float4 xv = *(const float4*)(Xs + (ty * 8 + j) * 132 + ib * 32 + ii4 * 4);
                acc[j].x += xv.x * w0.x + xv.y * w1.x + xv.z * w2.x + xv.w * w3.x;
                acc[j].y += xv.x * w0.y + xv.y * w1.y + xv.z * w2.y + xv.w * w3.y;
                acc[j].z += xv.x * w0.z + xv.y * w1.z + xv.z * w2.z + xv.w * w3.z;
                acc[j].w += xv.x * w0.w + xv.y * w1.w + xv.z * w2.w + xv.w * w3.w;
            }
        }
    }

    float4 b4 = make_float4(0.f, 0.f, 0.f, 0.f);
    if (t == 0) b4 = *(const float4*)(bias + tx * 4);

#pragma unroll
    for (int j = 0; j < 8; j++) {
        const int ng = nbase + ty * 8 + j;
        if (ng < N) {
            *(float4*)(xt + ((size_t)t * N + ng) * D_OUT + tx * 4) = acc[j];
            if (t == 0) {
                float4 o = make_float4(acc[j].x + b4.x, acc[j].y + b4.y,
                                       acc[j].z + b4.z, acc[j].w + b4.w);
                *(float4*)(out + (size_t)ng * D_OUT + tx * 4) = o;
            }
        }
    }
}

// ---------------------------------------------------------------------------
// k_scores: si[row][h*5+q] = dot(xt[row][32h:32h+32], attv[q][h][0:32])
//           sj[row][h*5+q] = dot(xt[row][32h:32h+32], attv[q][h][32:64])
// row = t*N+n. One wave per row, 4 rows/block.
// ---------------------------------------------------------------------------
__global__ __launch_bounds__(256) void k_scores(const float* __restrict__ xt,
                                                const float* __restrict__ attv,
                                                float* __restrict__ si,
                                                float* __restrict__ sj,
                                                int nrows) {
    __shared__ float att_s[N_CONF * HEADS * 64];
    const int tid = threadIdx.x;
    for (int f = tid; f < N_CONF * HEADS * 64; f += 256) att_s[f] = attv[f];
    __syncthreads();

    const int row = blockIdx.x * 4 + (tid >> 6);
    if (row >= nrows) return;
    const int lane = tid & 63;
    const int c0 = lane * 2;
    const int h  = c0 >> 5;
    const int cc = c0 & 31;

    const float2 xv = ((const float2*)(xt + (size_t)row * D_OUT))[lane];

    float f[N_CONF], b[N_CONF];
#pragma unroll
    for (int q = 0; q < N_CONF; q++) {
        const float* a = att_s + (q * HEADS + h) * 64;
        f[q] = xv.x * a[cc]      + xv.y * a[cc + 1];
        b[q] = xv.x * a[32 + cc] + xv.y * a[33 + cc];
    }
#pragma unroll
    for (int off = 1; off < 16; off <<= 1) {
#pragma unroll
        for (int q = 0; q < N_CONF; q++) {
            f[q] += __shfl_xor(f[q], off);
            b[q] += __shfl_xor(b[q], off);
        }
    }
    if ((lane & 15) == 0) {
#pragma unroll
        for (int q = 0; q < N_CONF; q++) {
            si[(size_t)row * 20 + h * 5 + q] = f[q];
            sj[(size_t)row * 20 + h * 5 + q] = b[q];
        }
    }
}

// ---------------------------------------------------------------------------
// CSR build over segments seg = dst*4 + type  (edges sorted by dst, then type)
// ---------------------------------------------------------------------------
__global__ __launch_bounds__(256) void k_hist(const int* __restrict__ dst,
                                              const int* __restrict__ et,
                                              int* __restrict__ counts, int E) {
    const int e = blockIdx.x * 256 + threadIdx.x;
    if (e < E) atomicAdd(&counts[dst[e] * 4 + et[e]], 1);
}

__global__ __launch_bounds__(256) void k_scan_part(const int* __restrict__ counts,
                                                   int* __restrict__ partial, int NS) {
    __shared__ int s[256];
    const int b = blockIdx.x, t = threadIdx.x;
    const int base = b * 1024 + t * 4;
    int sum = 0;
#pragma unroll
    for (int i = 0; i < 4; i++) if (base + i < NS) sum += counts[base + i];
    s[t] = sum; __syncthreads();
    for (int off = 128; off > 0; off >>= 1) {
        if (t < off) s[t] += s[t + off];
        __syncthreads();
    }
    if (t == 0) partial[b] = s[0];
}

// parallel exclusive scan of up to 256 partials in one block
__global__ __launch_bounds__(256) void k_scan_partials(int* __restrict__ partial, int nb) {
    __shared__ int s[256];
    const int t = threadIdx.x;
    int v = (t < nb) ? partial[t] : 0;
    s[t] = v; __syncthreads();
    for (int off = 1; off < 256; off <<= 1) {
        int x = (t >= off) ? s[t - off] : 0;
        __syncthreads();
        s[t] += x;
        __syncthreads();
    }
    if (t < nb) partial[t] = s[t] - v;   // exclusive
}

__global__ __launch_bounds__(256) void k_scan_chunk(const int* __restrict__ counts,
                                                    const int* __restrict__ partial,
                                                    int* __restrict__ offsets,
                                                    int* __restrict__ cursor, int NS) {
    __shared__ int s[256];
    const int b = blockIdx.x, t = threadIdx.x;
    const int base = b * 1024 + t * 4;
    int v[4]; int sum = 0;
#pragma unroll
    for (int i = 0; i < 4; i++) { v[i] = (base + i < NS) ? counts[base + i] : 0; sum += v[i]; }
    s[t] = sum; __syncthreads();
    for (int off = 1; off < 256; off <<= 1) {
        int x = (t >= off) ? s[t - off] : 0;
        __syncthreads();
        s[t] += x;
        __syncthreads();
    }
    int run = partial[b] + s[t] - sum;
#pragma unroll
    for (int i = 0; i < 4; i++) {
        const int idx = base + i;
        if (idx < NS) { offsets[idx] = run; cursor[idx] = run; run += v[i]; }
    }
}

__global__ __launch_bounds__(256) void k_fill(const int* __restrict__ src,
                                              const int* __restrict__ dst,
                                              const int* __restrict__ et,
                                              int* __restrict__ cursor,
                                              int* __restrict__ esrc,
                                              int* __restrict__ wpos, int E) {
    const int e = blockIdx.x * 256 + threadIdx.x;
    if (e < E) {
        const int pos = atomicAdd(&cursor[dst[e] * 4 + et[e]], 1);
        esrc[pos] = src[e];
        wpos[e]  = pos;
    }
}

// ---------------------------------------------------------------------------
// k_ew: one thread per (edge, head): w = exp(sum_q leaky(si+sj)*pk)
// writes wbuf[wpos[e]*4 + h] (CSR order) so k_node reads it sequentially.
// ---------------------------------------------------------------------------
__global__ __launch_bounds__(256) void k_ew(const int* __restrict__ src,
                                            const int* __restrict__ dst,
                                            const int* __restrict__ et,
                                            const int* __restrict__ wpos,
                                            const float* __restrict__ si,
                                            const float* __restrict__ sj,
                                            const float* __restrict__ cprobs,
                                            float* __restrict__ wbuf,
                                            int N, int E) {
    __shared__ float pk_s[N_CONF];
    if (threadIdx.x == 0) {
        float m = cprobs[0];
        for (int k = 1; k < N_CONF; k++) m = fmaxf(m, cprobs[k]);
        float ex[N_CONF], s = 0.f;
        for (int k = 0; k < N_CONF; k++) { ex[k] = __expf(cprobs[k] - m); s += ex[k]; }
        for (int k = 0; k < N_CONF; k++) pk_s[k] = ex[k] / s;
    }
    __syncthreads();

    const int gid = blockIdx.x * 256 + threadIdx.x;
    const int e = gid >> 2;
    if (e >= E) return;
    const int h = gid & 3;

    const int di = dst[e];
    const int sn = src[e];
    const int tt = et[e];

    const float* ip = si + ((size_t)tt * N + di) * 20 + h * 5;
    const float* jp = sj + ((size_t)tt * N + sn) * 20 + h * 5;

    float alpha = 0.f;
#pragma unroll
    for (int q = 0; q < N_CONF; q++) {
        float s = ip[q] + jp[q];
        s = (s > 0.f) ? s : 0.2f * s;
        alpha += s * pk_s[q];
    }
    wbuf[(size_t)wpos[e] * 4 + h] = __expf(alpha);
}

// ---------------------------------------------------------------------------
// k_node: one wave per dst node; 4 contiguous per-type runs; no predication:
//   acc += xj * w ; den += w ; then out += acc * imp[t]/den
// ---------------------------------------------------------------------------
__global__ __launch_bounds__(256) void k_node(const float* __restrict__ xt,
                                              const int* __restrict__ offsets,
                                              const int* __restrict__ counts,
                                              const int* __restrict__ esrc,
                                              const float* __restrict__ wbuf,
                                              const float* __restrict__ imp,
                                              float* __restrict__ out,
                                              int N) {
    __shared__ float imp_s[N_TYPES];
    if (threadIdx.x < N_TYPES) imp_s[threadIdx.x] = imp[threadIdx.x];
    __syncthreads();

    const int node = blockIdx.x * 4 + (threadIdx.x >> 6);
    if (node >= N) return;
    const int lane = threadIdx.x & 63;
    const int c0 = lane * 2;
    const int h  = c0 >> 5;

    float o0 = 0.f, o1 = 0.f;

#pragma unroll
    for (int t = 0; t < N_TYPES; t++) {
        const int start = offsets[node * 4 + t];
        const int cnt   = counts[node * 4 + t];
        if (cnt == 0) continue;
        float ax = 0.f, ay = 0.f, den = 0.f;
        const float* tbase = xt + (size_t)t * N * D_OUT;
        for (int k = 0; k < cnt; k++) {
            const int p  = start + k;
            const int sn = esrc[p];                       // wave-uniform
            const float w = wbuf[(size_t)p * 4 + h];
            const float2 xj = ((const float2*)(tbase + (size_t)sn * D_OUT))[lane];
            ax  += xj.x * w;
            ay  += xj.y * w;
            den += w;
        }
        const float f = imp_s[t] / den;
        o0 += ax * f;
        o1 += ay * f;
    }

    out[(size_t)node * D_OUT + c0]     += o0;
    out[(size_t)node * D_OUT + c0 + 1] += o1;
}

// ---------------------------------------------------------------------------
extern "C" void kernel_launch(void* const* d_in, const int* in_sizes, int n_in,
                              void* d_out, int out_size, void* d_ws, size_t ws_size,
                              hipStream_t stream) {
    const float* x    = (const float*)d_in[0];
    const int*   ei   = (const int*)d_in[1];
    const int*   et   = (const int*)d_in[2];
    const float* W    = (const float*)d_in[3];
    const float* attv = (const float*)d_in[4];
    const float* cpr  = (const float*)d_in[5];
    const float* imp  = (const float*)d_in[6];
    const float* bias = (const float*)d_in[7];

    const int N = in_sizes[0] / IN_CH;
    const int E = in_sizes[2];
    const int* src = ei;        // edge_index[0]
    const int* dst = ei + E;    // edge_index[1]
    const int NS = N * N_TYPES; // segments (dst,type)

    char* ws = (char*)d_ws;
    float* xt      = (float*)ws;  ws += (size_t)N_TYPES * N * D_OUT * sizeof(float);
    float* si      = (float*)ws;  ws += (size_t)N_TYPES * N * 20 * sizeof(float);
    float* sj      = (float*)ws;  ws += (size_t)N_TYPES * N * 20 * sizeof(float);
    float* wbuf    = (float*)ws;  ws += (size_t)E * HEADS * sizeof(float);
    int*   counts  = (int*)ws;    ws += (size_t)NS * sizeof(int);
    int*   offsets = (int*)ws;    ws += (size_t)NS * sizeof(int);
    int*   cursor  = (int*)ws;    ws += (size_t)NS * sizeof(int);
    int*   partial = (int*)ws;    ws += 256 * sizeof(int);
    int*   esrc    = (int*)ws;    ws += (size_t)E * sizeof(int);
    int*   wpos    = (int*)ws;    ws += (size_t)E * sizeof(int);
    float* out = (float*)d_out;

    hipMemsetAsync(counts, 0, (size_t)NS * sizeof(int), stream);

    const int nblocks = (N + 63) / 64;
    k_linear<<<dim3(N_TYPES * nblocks), 256, 0, stream>>>(x, W, bias, xt, out, N, nblocks);

    const int eb = (E + 255) / 256;
    const int nb = (NS + 1023) / 1024;
    k_hist<<<eb, 256, 0, stream>>>(dst, et, counts, E);
    k_scan_part<<<nb, 256, 0, stream>>>(counts, partial, NS);
    k_scan_partials<<<1, 256, 0, stream>>>(partial, nb);
    k_scan_chunk<<<nb, 256, 0, stream>>>(counts, partial, offsets, cursor, NS);
    k_fill<<<eb, 256, 0, stream>>>(src, dst, et, cursor, esrc, wpos, E);

    k_scores<<<(NS + 3) / 4, 256, 0, stream>>>(xt, attv, si, sj, NS);
    k_ew<<<(E * HEADS + 255) / 256, 256, 0, stream>>>(src, dst, et, wpos, si, sj, cpr, wbuf, N, E);

    k_node<<<(N + 3) / 4, 256, 0, stream>>>(xt, offsets, counts, esrc, wbuf, imp, out, N);
}

// Round 4
// 440.619 us; speedup vs baseline: 1.3027x; 1.3027x over previous
//
#include <hip/hip_runtime.h>

#define IN_CH   128
#define D_OUT   128   // OUT_CH*HEADS
#define HEADS   4
#define N_TYPES 4
#define N_CONF  5

typedef __attribute__((ext_vector_type(8))) short bf16x8;   // 8 bf16 (4 VGPRs)
typedef __attribute__((ext_vector_type(4))) float f32x4;

__device__ inline short bf16_rne(float f) {
    unsigned u = __float_as_uint(f);
    u += 0x7fff + ((u >> 16) & 1);
    return (short)(u >> 16);
}
// exact hi/lo split: f == hi + lo + O(2^-16 |f|)
__device__ inline void split_hl(float f, short& h, short& l) {
    unsigned u = __float_as_uint(f);
    h = (short)(u >> 16);
    float r = f - __uint_as_float(u & 0xffff0000u);   // exact
    l = (short)(__float_as_uint(r) >> 16);
}

// ---------------------------------------------------------------------------
// k_wprep: Wth/Wtl[t][d][k] = hi/lo bf16 of W[t][k][d]  (transposed for B-frag
// b128 reads: B^T[n][k] row-major, gemm_bt pattern)
// ---------------------------------------------------------------------------
__global__ __launch_bounds__(256) void k_wprep(const float* __restrict__ W,
                                               short* __restrict__ Wth,
                                               short* __restrict__ Wtl) {
    const int g = blockIdx.x * 256 + threadIdx.x;      // total 4*128*128
    if (g >= N_TYPES * 128 * 128) return;
    const int t = g >> 14;
    const int k = (g >> 7) & 127;
    const int d = g & 127;
    const float v = W[g];                               // coalesced (d fastest)
    short h, l; split_hl(v, h, l);
    const int o = (t << 14) + (d << 7) + k;
    Wth[o] = h; Wtl[o] = l;
}

// ---------------------------------------------------------------------------
// k_linear: MFMA bf16 hi/lo GEMM, 64 nodes x 128 d x 4 types per block.
//  - writes xtb (bf16) for the gather path
//  - t==0: out = acc + bias (fp32)
//  - fused scores epilogue: wave w == head w; si/sj[t*N+n][h*5+q] from fp32 acc
// ---------------------------------------------------------------------------
__global__ __launch_bounds__(256) void k_linear(const float* __restrict__ x,
                                                const short* __restrict__ Wth,
                                                const short* __restrict__ Wtl,
                                                const float* __restrict__ bias,
                                                const float* __restrict__ attv,
                                                short* __restrict__ xtb,
                                                float* __restrict__ si,
                                                float* __restrict__ sj,
                                                float* __restrict__ out,
                                                int N) {
    __shared__ short Xh[64 * 136];          // padded rows: 272 B stride
    __shared__ short Xl[64 * 136];
    __shared__ float att_s[N_CONF * HEADS * 64];

    const int tid   = threadIdx.x;
    const int nbase = blockIdx.x * 64;

    for (int f = tid; f < N_CONF * HEADS * 64; f += 256) att_s[f] = attv[f];

    // stage X tile -> hi/lo bf16 in LDS
#pragma unroll
    for (int i = 0; i < 8; i++) {
        const int f   = tid + i * 256;       // 0..2047
        const int row = f >> 5;
        const int c4  = (f & 31) * 4;
        float4 v = make_float4(0.f, 0.f, 0.f, 0.f);
        const int ng = nbase + row;
        if (ng < N) v = *(const float4*)(x + (size_t)ng * IN_CH + c4);
        short h, l;
        split_hl(v.x, h, l); Xh[row * 136 + c4 + 0] = h; Xl[row * 136 + c4 + 0] = l;
        split_hl(v.y, h, l); Xh[row * 136 + c4 + 1] = h; Xl[row * 136 + c4 + 1] = l;
        split_hl(v.z, h, l); Xh[row * 136 + c4 + 2] = h; Xl[row * 136 + c4 + 2] = l;
        split_hl(v.w, h, l); Xh[row * 136 + c4 + 3] = h; Xl[row * 136 + c4 + 3] = l;
    }
    __syncthreads();

    const int w    = tid >> 6;    // wave id == head id == d-range w*32..+31
    const int lane = tid & 63;
    const int n16  = lane & 15;
    const int quad = lane >> 4;

    // attention vectors for the fused score epilogue (per-lane constants)
    float av_f[N_CONF][2], av_b[N_CONF][2];
#pragma unroll
    for (int q = 0; q < N_CONF; q++)
#pragma unroll
        for (int dt = 0; dt < 2; dt++) {
            av_f[q][dt] = att_s[(q * HEADS + w) * 64 + dt * 16 + n16];
            av_b[q][dt] = att_s[(q * HEADS + w) * 64 + 32 + dt * 16 + n16];
        }
    float bsr[2];
#pragma unroll
    for (int dt = 0; dt < 2; dt++) bsr[dt] = bias[w * 32 + dt * 16 + n16];

    for (int t = 0; t < N_TYPES; t++) {
        // B-frags from global (L2-hot, same for all blocks)
        bf16x8 Bh[2][4], Bl[2][4];
        const size_t wof = ((size_t)t * 128 + w * 32) * 128;
#pragma unroll
        for (int dt = 0; dt < 2; dt++)
#pragma unroll
            for (int kc = 0; kc < 4; kc++) {
                const size_t off = wof + (size_t)(dt * 16 + n16) * 128 + kc * 32 + quad * 8;
                Bh[dt][kc] = *(const bf16x8*)(Wth + off);
                Bl[dt][kc] = *(const bf16x8*)(Wtl + off);
            }

        f32x4 acc[4][2];
#pragma unroll
        for (int mt = 0; mt < 4; mt++)
#pragma unroll
            for (int dt = 0; dt < 2; dt++) acc[mt][dt] = (f32x4){0.f, 0.f, 0.f, 0.f};

#pragma unroll
        for (int kc = 0; kc < 4; kc++) {
            bf16x8 Ah[4], Al[4];
#pragma unroll
            for (int mt = 0; mt < 4; mt++) {
                const int r = (mt * 16 + n16) * 136 + kc * 32 + quad * 8;
                Ah[mt] = *(const bf16x8*)(Xh + r);
                Al[mt] = *(const bf16x8*)(Xl + r);
            }
#pragma unroll
            for (int mt = 0; mt < 4; mt++)
#pragma unroll
                for (int dt = 0; dt < 2; dt++) {
                    acc[mt][dt] = __builtin_amdgcn_mfma_f32_16x16x32_bf16(Ah[mt], Bh[dt][kc], acc[mt][dt], 0, 0, 0);
                    acc[mt][dt] = __builtin_amdgcn_mfma_f32_16x16x32_bf16(Ah[mt], Bl[dt][kc], acc[mt][dt], 0, 0, 0);
                    acc[mt][dt] = __builtin_amdgcn_mfma_f32_16x16x32_bf16(Al[mt], Bh[dt][kc], acc[mt][dt], 0, 0, 0);
                }
        }

        // epilogue: xtb (bf16), out (t==0), fused per-head scores
        const size_t trow = (size_t)t * N;
#pragma unroll
        for (int mt = 0; mt < 4; mt++) {
#pragma unroll
            for (int dt = 0; dt < 2; dt++)
#pragma unroll
                for (int r = 0; r < 4; r++) {
                    const int node = nbase + mt * 16 + quad * 4 + r;
                    if (node < N) {
                        const float v = acc[mt][dt][r];
                        const int d = w * 32 + dt * 16 + n16;
                        xtb[(trow + node) * (size_t)D_OUT + d] = bf16_rne(v);
                        if (t == 0) out[(size_t)node * D_OUT + d] = v + bsr[dt];
                    }
                }
#pragma unroll
            for (int r = 0; r < 4; r++) {
                float pf[N_CONF], pb[N_CONF];
#pragma unroll
                for (int q = 0; q < N_CONF; q++) {
                    pf[q] = acc[mt][0][r] * av_f[q][0] + acc[mt][1][r] * av_f[q][1];
                    pb[q] = acc[mt][0][r] * av_b[q][0] + acc[mt][1][r] * av_b[q][1];
                }
#pragma unroll
                for (int off = 1; off < 16; off <<= 1)
#pragma unroll
                    for (int q = 0; q < N_CONF; q++) {
                        pf[q] += __shfl_xor(pf[q], off);
                        pb[q] += __shfl_xor(pb[q], off);
                    }
                if (n16 == 0) {
                    const int node = nbase + mt * 16 + quad * 4 + r;
                    if (node < N) {
                        const size_t b = (trow + node) * 20 + w * 5;
#pragma unroll
                        for (int q = 0; q < N_CONF; q++) { si[b + q] = pf[q]; sj[b + q] = pb[q]; }
                    }
                }
            }
        }
    }
}

// ---------------------------------------------------------------------------
// CSR build over segments seg = dst*4 + type
// ---------------------------------------------------------------------------
__global__ __launch_bounds__(256) void k_hist(const int* __restrict__ dst,
                                              const int* __restrict__ et,
                                              int* __restrict__ counts, int E) {
    const int e = blockIdx.x * 256 + threadIdx.x;
    if (e < E) atomicAdd(&counts[dst[e] * 4 + et[e]], 1);
}

__global__ __launch_bounds__(256) void k_scan_part(const int* __restrict__ counts,
                                                   int* __restrict__ partial, int NS) {
    __shared__ int s[256];
    const int b = blockIdx.x, t = threadIdx.x;
    const int base = b * 1024 + t * 4;
    int sum = 0;
#pragma unroll
    for (int i = 0; i < 4; i++) if (base + i < NS) sum += counts[base + i];
    s[t] = sum; __syncthreads();
    for (int off = 128; off > 0; off >>= 1) {
        if (t < off) s[t] += s[t + off];
        __syncthreads();
    }
    if (t == 0) partial[b] = s[0];
}

__global__ __launch_bounds__(256) void k_scan_partials(int* __restrict__ partial, int nb) {
    __shared__ int s[256];
    const int t = threadIdx.x;
    int v = (t < nb) ? partial[t] : 0;
    s[t] = v; __syncthreads();
    for (int off = 1; off < 256; off <<= 1) {
        int x = (t >= off) ? s[t - off] : 0;
        __syncthreads();
        s[t] += x;
        __syncthreads();
    }
    if (t < nb) partial[t] = s[t] - v;   // exclusive
}

__global__ __launch_bounds__(256) void k_scan_chunk(const int* __restrict__ counts,
                                                    const int* __restrict__ partial,
                                                    int* __restrict__ offsets,
                                                    int* __restrict__ cursor, int NS) {
    __shared__ int s[256];
    const int b = blockIdx.x, t = threadIdx.x;
    const int base = b * 1024 + t * 4;
    int v[4]; int sum = 0;
#pragma unroll
    for (int i = 0; i < 4; i++) { v[i] = (base + i < NS) ? counts[base + i] : 0; sum += v[i]; }
    s[t] = sum; __syncthreads();
    for (int off = 1; off < 256; off <<= 1) {
        int x = (t >= off) ? s[t - off] : 0;
        __syncthreads();
        s[t] += x;
        __syncthreads();
    }
    int run = partial[b] + s[t] - sum;
#pragma unroll
    for (int i = 0; i < 4; i++) {
        const int idx = base + i;
        if (idx < NS) { offsets[idx] = run; cursor[idx] = run; run += v[i]; }
    }
}

__global__ __launch_bounds__(256) void k_fill(const int* __restrict__ src,
                                              const int* __restrict__ dst,
                                              const int* __restrict__ et,
                                              int* __restrict__ cursor,
                                              int* __restrict__ esrc,
                                              int* __restrict__ eseg, int E) {
    const int e = blockIdx.x * 256 + threadIdx.x;
    if (e < E) {
        const int seg = dst[e] * 4 + et[e];
        const int pos = atomicAdd(&cursor[seg], 1);
        esrc[pos] = src[e];
        eseg[pos] = seg;
    }
}

// ---------------------------------------------------------------------------
// k_ew: CSR-position-parallel, one thread per (pos, head); coalesced in & out.
// ---------------------------------------------------------------------------
__global__ __launch_bounds__(256) void k_ew(const int* __restrict__ esrc,
                                            const int* __restrict__ eseg,
                                            const float* __restrict__ si,
                                            const float* __restrict__ sj,
                                            const float* __restrict__ cprobs,
                                            float* __restrict__ wbuf,
                                            int N, int E) {
    __shared__ float pk_s[N_CONF];
    if (threadIdx.x == 0) {
        float m = cprobs[0];
        for (int k = 1; k < N_CONF; k++) m = fmaxf(m, cprobs[k]);
        float ex[N_CONF], s = 0.f;
        for (int k = 0; k < N_CONF; k++) { ex[k] = __expf(cprobs[k] - m); s += ex[k]; }
        for (int k = 0; k < N_CONF; k++) pk_s[k] = ex[k] / s;
    }
    __syncthreads();

    const int gid = blockIdx.x * 256 + threadIdx.x;
    const int p = gid >> 2;
    if (p >= E) return;
    const int h = gid & 3;

    const int seg = eseg[p];
    const int sn  = esrc[p];
    const int di  = seg >> 2;
    const int tt  = seg & 3;

    const float* ip = si + ((size_t)tt * N + di) * 20 + h * 5;
    const float* jp = sj + ((size_t)tt * N + sn) * 20 + h * 5;

    float alpha = 0.f;
#pragma unroll
    for (int q = 0; q < N_CONF; q++) {
        float s = ip[q] + jp[q];
        s = (s > 0.f) ? s : 0.2f * s;
        alpha += s * pk_s[q];
    }
    wbuf[(size_t)p * 4 + h] = __expf(alpha);
}

// ---------------------------------------------------------------------------
// k_node: one wave per dst node; 4 contiguous per-type runs; bf16 gathers.
// ---------------------------------------------------------------------------
__global__ __launch_bounds__(256) void k_node(const short* __restrict__ xtb,
                                              const int* __restrict__ offsets,
                                              const int* __restrict__ counts,
                                              const int* __restrict__ esrc,
                                              const float* __restrict__ wbuf,
                                              const float* __restrict__ imp,
                                              float* __restrict__ out,
                                              int N) {
    __shared__ float imp_s[N_TYPES];
    if (threadIdx.x < N_TYPES) imp_s[threadIdx.x] = imp[threadIdx.x];
    __syncthreads();

    const int node = blockIdx.x * 4 + (threadIdx.x >> 6);
    if (node >= N) return;
    const int lane = threadIdx.x & 63;
    const int c0 = lane * 2;
    const int quad = lane >> 4;   // == head

    float o0 = 0.f, o1 = 0.f;

#pragma unroll
    for (int t = 0; t < N_TYPES; t++) {
        const int start = offsets[node * 4 + t];
        const int cnt   = counts[node * 4 + t];
        if (cnt == 0) continue;
        float ax = 0.f, ay = 0.f, den = 0.f;
        const short* tbase = xtb + (size_t)t * N * D_OUT;
        for (int k = 0; k < cnt; k++) {
            const int p  = start + k;
            const int sn = esrc[p];                         // wave-uniform
            const float w = wbuf[(size_t)p * 4 + quad];
            const unsigned u = ((const unsigned*)(tbase + (size_t)sn * D_OUT))[lane];
            ax  += __uint_as_float(u << 16) * w;
            ay  += __uint_as_float(u & 0xffff0000u) * w;
            den += w;
        }
        const float f = imp_s[t] / den;
        o0 += ax * f;
        o1 += ay * f;
    }

    out[(size_t)node * D_OUT + c0]     += o0;
    out[(size_t)node * D_OUT + c0 + 1] += o1;
}

// ---------------------------------------------------------------------------
extern "C" void kernel_launch(void* const* d_in, const int* in_sizes, int n_in,
                              void* d_out, int out_size, void* d_ws, size_t ws_size,
                              hipStream_t stream) {
    const float* x    = (const float*)d_in[0];
    const int*   ei   = (const int*)d_in[1];
    const int*   et   = (const int*)d_in[2];
    const float* W    = (const float*)d_in[3];
    const float* attv = (const float*)d_in[4];
    const float* cpr  = (const float*)d_in[5];
    const float* imp  = (const float*)d_in[6];
    const float* bias = (const float*)d_in[7];

    const int N = in_sizes[0] / IN_CH;
    const int E = in_sizes[2];
    const int* src = ei;        // edge_index[0]
    const int* dst = ei + E;    // edge_index[1]
    const int NS = N * N_TYPES;

    char* ws = (char*)d_ws;
    float* si      = (float*)ws;  ws += (size_t)N_TYPES * N * 20 * sizeof(float);
    float* sj      = (float*)ws;  ws += (size_t)N_TYPES * N * 20 * sizeof(float);
    float* wbuf    = (float*)ws;  ws += (size_t)E * HEADS * sizeof(float);
    short* Wth     = (short*)ws;  ws += (size_t)N_TYPES * 128 * 128 * sizeof(short);
    short* Wtl     = (short*)ws;  ws += (size_t)N_TYPES * 128 * 128 * sizeof(short);
    short* xtb     = (short*)ws;  ws += (size_t)N_TYPES * N * D_OUT * sizeof(short);
    int*   counts  = (int*)ws;    ws += (size_t)NS * sizeof(int);
    int*   offsets = (int*)ws;    ws += (size_t)NS * sizeof(int);
    int*   cursor  = (int*)ws;    ws += (size_t)NS * sizeof(int);
    int*   partial = (int*)ws;    ws += 256 * sizeof(int);
    int*   esrc    = (int*)ws;    ws += (size_t)E * sizeof(int);
    int*   eseg    = (int*)ws;    ws += (size_t)E * sizeof(int);
    float* out = (float*)d_out;

    hipMemsetAsync(counts, 0, (size_t)NS * sizeof(int), stream);

    k_wprep<<<(N_TYPES * 128 * 128 + 255) / 256, 256, 0, stream>>>(W, Wth, Wtl);

    const int nblocks = (N + 63) / 64;
    k_linear<<<nblocks, 256, 0, stream>>>(x, Wth, Wtl, bias, attv, xtb, si, sj, out, N);

    const int eb = (E + 255) / 256;
    const int nb = (NS + 1023) / 1024;
    k_hist<<<eb, 256, 0, stream>>>(dst, et, counts, E);
    k_scan_part<<<nb, 256, 0, stream>>>(counts, partial, NS);
    k_scan_partials<<<1, 256, 0, stream>>>(partial, nb);
    k_scan_chunk<<<nb, 256, 0, stream>>>(counts, partial, offsets, cursor, NS);
    k_fill<<<eb, 256, 0, stream>>>(src, dst, et, cursor, esrc, eseg, E);

    k_ew<<<(E * HEADS + 255) / 256, 256, 0, stream>>>(esrc, eseg, si, sj, cpr, wbuf, N, E);

    k_node<<<(N + 3) / 4, 256, 0, stream>>>(xtb, offsets, counts, esrc, wbuf, imp, out, N);
}

// Round 5
// 388.504 us; speedup vs baseline: 1.4774x; 1.1341x over previous
//
#include <hip/hip_runtime.h>

#define IN_CH   128
#define D_OUT   128   // OUT_CH*HEADS
#define HEADS   4
#define N_TYPES 4
#define N_CONF  5
#define DCOLS   192   // 128 xt cols + 48 score cols (40 real + 8 pad)
#define SSTRIDE 24    // si/sj per-row stride: h*6+q (q<5 used)

typedef __attribute__((ext_vector_type(8))) short bf16x8;   // 8 bf16 (4 VGPRs)
typedef __attribute__((ext_vector_type(4))) float f32x4;

__device__ inline short bf16_rne(float f) {
    unsigned u = __float_as_uint(f);
    u += 0x7fff + ((u >> 16) & 1);
    return (short)(u >> 16);
}
// exact hi/lo split: f ~= hi + lo with ~2^-16 relative residual
__device__ inline void split_hl(float f, short& h, short& l) {
    unsigned u = __float_as_uint(f);
    h = (short)(u >> 16);
    float r = f - __uint_as_float(u & 0xffff0000u);   // exact
    l = (short)(__float_as_uint(r) >> 16);
}

// ---------------------------------------------------------------------------
// k_matt: M[t][k][col] = sum_{d'<32} W[t][k][32h+d'] * attv[q][h][fb*32+d']
//         col = fb*24 + h*6 + q  (q==5 -> 0 padding)
// ---------------------------------------------------------------------------
__global__ __launch_bounds__(256) void k_matt(const float* __restrict__ W,
                                              const float* __restrict__ attv,
                                              float* __restrict__ M) {
    const int g = blockIdx.x * 256 + threadIdx.x;   // 4*128*48
    if (g >= N_TYPES * 128 * 48) return;
    const int col = g % 48;
    const int k   = (g / 48) % 128;
    const int t   = g / (48 * 128);
    const int fb  = col / 24;
    const int rem = col % 24;
    const int h   = rem / 6;
    const int q   = rem % 6;
    float acc = 0.f;
    if (q < N_CONF) {
        const float* wr = W + ((size_t)t * 128 + k) * 128 + 32 * h;
        const float* ar = attv + ((size_t)q * HEADS + h) * 64 + fb * 32;
#pragma unroll
        for (int d = 0; d < 32; d++) acc += wr[d] * ar[d];
    }
    M[g] = acc;
}

// ---------------------------------------------------------------------------
// k_wprep: Wth/Wtl[t][dcol][k] = hi/lo bf16 of B'[t][k][dcol]
//          B' = [ W[t] (128 cols) | M[t] (48 cols) | implicit ]  transposed
// ---------------------------------------------------------------------------
__global__ __launch_bounds__(256) void k_wprep(const float* __restrict__ W,
                                               const float* __restrict__ M,
                                               short* __restrict__ Wth,
                                               short* __restrict__ Wtl) {
    const int g = blockIdx.x * 256 + threadIdx.x;   // 4*128*192, dcol fastest
    if (g >= N_TYPES * 128 * DCOLS) return;
    const int dcol = g % DCOLS;
    const int k    = (g / DCOLS) % 128;
    const int t    = g / (DCOLS * 128);
    float v = 0.f;
    if (dcol < 128)      v = W[((size_t)t * 128 + k) * 128 + dcol];
    else if (dcol < 176) v = M[((size_t)t * 128 + k) * 48 + (dcol - 128)];
    short h, l; split_hl(v, h, l);
    const size_t o = ((size_t)t * DCOLS + dcol) * 128 + k;
    Wth[o] = h; Wtl[o] = l;
}

// ---------------------------------------------------------------------------
// k_linear: bf16 hi/lo MFMA GEMM, [64 nodes x 128 k] x [128 k x 192 cols].
// grid (nblocks, type). Wave w owns col tiles 3w..3w+2.
// cols <128 -> xtb(bf16) (+out for t==0); 128..175 -> si/sj (fp32).
// ---------------------------------------------------------------------------
__global__ __launch_bounds__(256) void k_linear(const float* __restrict__ x,
                                                const short* __restrict__ Wth,
                                                const short* __restrict__ Wtl,
                                                const float* __restrict__ bias,
                                                short* __restrict__ xtb,
                                                float* __restrict__ si,
                                                float* __restrict__ sj,
                                                float* __restrict__ out,
                                                int N) {
    __shared__ short Xh[64 * 136];          // row stride 136 shorts (272 B)
    __shared__ short Xl[64 * 136];

    const int tid   = threadIdx.x;
    const int nbase = blockIdx.x * 64;
    const int t     = blockIdx.y;

    // stage X tile -> hi/lo bf16 (b64 LDS writes, 2-way free)
#pragma unroll
    for (int i = 0; i < 8; i++) {
        const int f   = tid + i * 256;       // 0..2047
        const int row = f >> 5;
        const int c4  = (f & 31) * 4;
        float4 v = make_float4(0.f, 0.f, 0.f, 0.f);
        const int ng = nbase + row;
        if (ng < N) v = *(const float4*)(x + (size_t)ng * IN_CH + c4);
        short4 h4, l4;
        split_hl(v.x, h4.x, l4.x);
        split_hl(v.y, h4.y, l4.y);
        split_hl(v.z, h4.z, l4.z);
        split_hl(v.w, h4.w, l4.w);
        *(short4*)(Xh + row * 136 + c4) = h4;
        *(short4*)(Xl + row * 136 + c4) = l4;
    }
    __syncthreads();

    const int w    = tid >> 6;
    const int lane = tid & 63;
    const int n16  = lane & 15;
    const int quad = lane >> 4;

    const size_t trow = (size_t)t * N;

#pragma unroll
    for (int tt = 0; tt < 3; tt++) {
        const int dcol = (w * 3 + tt) * 16 + n16;

        // B frags for this col tile (all 4 k-chunks), L2-hot
        bf16x8 Bh[4], Bl[4];
        const size_t wof = ((size_t)t * DCOLS + dcol) * 128;
#pragma unroll
        for (int kc = 0; kc < 4; kc++) {
            Bh[kc] = *(const bf16x8*)(Wth + wof + kc * 32 + quad * 8);
            Bl[kc] = *(const bf16x8*)(Wtl + wof + kc * 32 + quad * 8);
        }

        f32x4 acc[4];
#pragma unroll
        for (int mt = 0; mt < 4; mt++) acc[mt] = (f32x4){0.f, 0.f, 0.f, 0.f};

#pragma unroll
        for (int kc = 0; kc < 4; kc++) {
            bf16x8 Ah[4], Al[4];
#pragma unroll
            for (int mt = 0; mt < 4; mt++) {
                const int r = (mt * 16 + n16) * 136 + kc * 32 + quad * 8;
                Ah[mt] = *(const bf16x8*)(Xh + r);
                Al[mt] = *(const bf16x8*)(Xl + r);
            }
#pragma unroll
            for (int mt = 0; mt < 4; mt++) {
                acc[mt] = __builtin_amdgcn_mfma_f32_16x16x32_bf16(Ah[mt], Bh[kc], acc[mt], 0, 0, 0);
                acc[mt] = __builtin_amdgcn_mfma_f32_16x16x32_bf16(Ah[mt], Bl[kc], acc[mt], 0, 0, 0);
                acc[mt] = __builtin_amdgcn_mfma_f32_16x16x32_bf16(Al[mt], Bh[kc], acc[mt], 0, 0, 0);
            }
        }

        // epilogue: C-layout col=n16(in dcol), row=quad*4+r
        if (dcol < 128) {
            const float bv = bias[dcol];
#pragma unroll
            for (int mt = 0; mt < 4; mt++)
#pragma unroll
                for (int r = 0; r < 4; r++) {
                    const int node = nbase + mt * 16 + quad * 4 + r;
                    if (node < N) {
                        const float v = acc[mt][r];
                        xtb[(trow + node) * (size_t)D_OUT + dcol] = bf16_rne(v);
                        if (t == 0) out[(size_t)node * D_OUT + dcol] = v + bv;
                    }
                }
        } else if (dcol < 176) {
            const int c   = dcol - 128;
            const int rem = c % 24;
            float* buf = (c < 24) ? si : sj;
#pragma unroll
            for (int mt = 0; mt < 4; mt++)
#pragma unroll
                for (int r = 0; r < 4; r++) {
                    const int node = nbase + mt * 16 + quad * 4 + r;
                    if (node < N)
                        buf[(trow + node) * SSTRIDE + rem] = acc[mt][r];
                }
        }
    }
}

// ---------------------------------------------------------------------------
// CSR build over segments seg = dst*4 + type
// ---------------------------------------------------------------------------
__global__ __launch_bounds__(256) void k_hist(const int* __restrict__ dst,
                                              const int* __restrict__ et,
                                              int* __restrict__ counts, int E) {
    const int e = blockIdx.x * 256 + threadIdx.x;
    if (e < E) atomicAdd(&counts[dst[e] * 4 + et[e]], 1);
}

__global__ __launch_bounds__(256) void k_scan_part(const int* __restrict__ counts,
                                                   int* __restrict__ partial, int NS) {
    __shared__ int s[256];
    const int b = blockIdx.x, t = threadIdx.x;
    const int base = b * 1024 + t * 4;
    int sum = 0;
#pragma unroll
    for (int i = 0; i < 4; i++) if (base + i < NS) sum += counts[base + i];
    s[t] = sum; __syncthreads();
    for (int off = 128; off > 0; off >>= 1) {
        if (t < off) s[t] += s[t + off];
        __syncthreads();
    }
    if (t == 0) partial[b] = s[0];
}

__global__ __launch_bounds__(256) void k_scan_partials(int* __restrict__ partial, int nb) {
    __shared__ int s[256];
    const int t = threadIdx.x;
    int v = (t < nb) ? partial[t] : 0;
    s[t] = v; __syncthreads();
    for (int off = 1; off < 256; off <<= 1) {
        int x = (t >= off) ? s[t - off] : 0;
        __syncthreads();
        s[t] += x;
        __syncthreads();
    }
    if (t < nb) partial[t] = s[t] - v;   // exclusive
}

__global__ __launch_bounds__(256) void k_scan_chunk(const int* __restrict__ counts,
                                                    const int* __restrict__ partial,
                                                    int* __restrict__ offsets,
                                                    int* __restrict__ cursor, int NS) {
    __shared__ int s[256];
    const int b = blockIdx.x, t = threadIdx.x;
    const int base = b * 1024 + t * 4;
    int v[4]; int sum = 0;
#pragma unroll
    for (int i = 0; i < 4; i++) { v[i] = (base + i < NS) ? counts[base + i] : 0; sum += v[i]; }
    s[t] = sum; __syncthreads();
    for (int off = 1; off < 256; off <<= 1) {
        int x = (t >= off) ? s[t - off] : 0;
        __syncthreads();
        s[t] += x;
        __syncthreads();
    }
    int run = partial[b] + s[t] - sum;
#pragma unroll
    for (int i = 0; i < 4; i++) {
        const int idx = base + i;
        if (idx < NS) { offsets[idx] = run; cursor[idx] = run; run += v[i]; }
    }
}

__global__ __launch_bounds__(256) void k_fill(const int* __restrict__ src,
                                              const int* __restrict__ dst,
                                              const int* __restrict__ et,
                                              int* __restrict__ cursor,
                                              int* __restrict__ esrc,
                                              int* __restrict__ eseg, int E) {
    const int e = blockIdx.x * 256 + threadIdx.x;
    if (e < E) {
        const int seg = dst[e] * 4 + et[e];
        const int pos = atomicAdd(&cursor[seg], 1);
        esrc[pos] = src[e];
        eseg[pos] = seg;
    }
}

// ---------------------------------------------------------------------------
// k_ew: one thread per (CSR pos, head); coalesced in & out.
// ---------------------------------------------------------------------------
__global__ __launch_bounds__(256) void k_ew(const int* __restrict__ esrc,
                                            const int* __restrict__ eseg,
                                            const float* __restrict__ si,
                                            const float* __restrict__ sj,
                                            const float* __restrict__ cprobs,
                                            float* __restrict__ wbuf,
                                            int N, int E) {
    __shared__ float pk_s[N_CONF];
    if (threadIdx.x == 0) {
        float m = cprobs[0];
        for (int k = 1; k < N_CONF; k++) m = fmaxf(m, cprobs[k]);
        float ex[N_CONF], s = 0.f;
        for (int k = 0; k < N_CONF; k++) { ex[k] = __expf(cprobs[k] - m); s += ex[k]; }
        for (int k = 0; k < N_CONF; k++) pk_s[k] = ex[k] / s;
    }
    __syncthreads();

    const int gid = blockIdx.x * 256 + threadIdx.x;
    const int p = gid >> 2;
    if (p >= E) return;
    const int h = gid & 3;

    const int seg = eseg[p];
    const int sn  = esrc[p];
    const int di  = seg >> 2;
    const int tt  = seg & 3;

    const float* ip = si + ((size_t)tt * N + di) * SSTRIDE + h * 6;
    const float* jp = sj + ((size_t)tt * N + sn) * SSTRIDE + h * 6;

    float alpha = 0.f;
#pragma unroll
    for (int q = 0; q < N_CONF; q++) {
        float s = ip[q] + jp[q];
        s = (s > 0.f) ? s : 0.2f * s;
        alpha += s * pk_s[q];
    }
    wbuf[(size_t)p * 4 + h] = __expf(alpha);
}

// ---------------------------------------------------------------------------
// k_node: one wave per dst node; 4 contiguous per-type runs; bf16 gathers.
// ---------------------------------------------------------------------------
__global__ __launch_bounds__(256) void k_node(const short* __restrict__ xtb,
                                              const int* __restrict__ offsets,
                                              const int* __restrict__ counts,
                                              const int* __restrict__ esrc,
                                              const float* __restrict__ wbuf,
                                              const float* __restrict__ imp,
                                              float* __restrict__ out,
                                              int N) {
    __shared__ float imp_s[N_TYPES];
    if (threadIdx.x < N_TYPES) imp_s[threadIdx.x] = imp[threadIdx.x];
    __syncthreads();

    const int node = blockIdx.x * 4 + (threadIdx.x >> 6);
    if (node >= N) return;
    const int lane = threadIdx.x & 63;
    const int c0 = lane * 2;
    const int quad = lane >> 4;   // == head

    float o0 = 0.f, o1 = 0.f;

#pragma unroll
    for (int t = 0; t < N_TYPES; t++) {
        const int start = offsets[node * 4 + t];
        const int cnt   = counts[node * 4 + t];
        if (cnt == 0) continue;
        float ax = 0.f, ay = 0.f, den = 0.f;
        const short* tbase = xtb + (size_t)t * N * D_OUT;
        for (int k = 0; k < cnt; k++) {
            const int p  = start + k;
            const int sn = esrc[p];                         // wave-uniform
            const float w = wbuf[(size_t)p * 4 + quad];
            const unsigned u = ((const unsigned*)(tbase + (size_t)sn * D_OUT))[lane];
            ax  += __uint_as_float(u << 16) * w;
            ay  += __uint_as_float(u & 0xffff0000u) * w;
            den += w;
        }
        const float f = imp_s[t] / den;
        o0 += ax * f;
        o1 += ay * f;
    }

    out[(size_t)node * D_OUT + c0]     += o0;
    out[(size_t)node * D_OUT + c0 + 1] += o1;
}

// ---------------------------------------------------------------------------
extern "C" void kernel_launch(void* const* d_in, const int* in_sizes, int n_in,
                              void* d_out, int out_size, void* d_ws, size_t ws_size,
                              hipStream_t stream) {
    const float* x    = (const float*)d_in[0];
    const int*   ei   = (const int*)d_in[1];
    const int*   et   = (const int*)d_in[2];
    const float* W    = (const float*)d_in[3];
    const float* attv = (const float*)d_in[4];
    const float* cpr  = (const float*)d_in[5];
    const float* imp  = (const float*)d_in[6];
    const float* bias = (const float*)d_in[7];

    const int N = in_sizes[0] / IN_CH;
    const int E = in_sizes[2];
    const int* src = ei;        // edge_index[0]
    const int* dst = ei + E;    // edge_index[1]
    const int NS = N * N_TYPES;

    char* ws = (char*)d_ws;
    float* si      = (float*)ws;  ws += (size_t)N_TYPES * N * SSTRIDE * sizeof(float);
    float* sj      = (float*)ws;  ws += (size_t)N_TYPES * N * SSTRIDE * sizeof(float);
    float* wbuf    = (float*)ws;  ws += (size_t)E * HEADS * sizeof(float);
    float* M       = (float*)ws;  ws += (size_t)N_TYPES * 128 * 48 * sizeof(float);
    short* Wth     = (short*)ws;  ws += (size_t)N_TYPES * DCOLS * 128 * sizeof(short);
    short* Wtl     = (short*)ws;  ws += (size_t)N_TYPES * DCOLS * 128 * sizeof(short);
    short* xtb     = (short*)ws;  ws += (size_t)N_TYPES * N * D_OUT * sizeof(short);
    int*   counts  = (int*)ws;    ws += (size_t)NS * sizeof(int);
    int*   offsets = (int*)ws;    ws += (size_t)NS * sizeof(int);
    int*   cursor  = (int*)ws;    ws += (size_t)NS * sizeof(int);
    int*   partial = (int*)ws;    ws += 256 * sizeof(int);
    int*   esrc    = (int*)ws;    ws += (size_t)E * sizeof(int);
    int*   eseg    = (int*)ws;    ws += (size_t)E * sizeof(int);
    float* out = (float*)d_out;

    hipMemsetAsync(counts, 0, (size_t)NS * sizeof(int), stream);

    k_matt<<<(N_TYPES * 128 * 48 + 255) / 256, 256, 0, stream>>>(W, attv, M);
    k_wprep<<<(N_TYPES * 128 * DCOLS + 255) / 256, 256, 0, stream>>>(W, M, Wth, Wtl);

    const int nblocks = (N + 63) / 64;
    k_linear<<<dim3(nblocks, N_TYPES), 256, 0, stream>>>(x, Wth, Wtl, bias, xtb, si, sj, out, N);

    const int eb = (E + 255) / 256;
    const int nb = (NS + 1023) / 1024;
    k_hist<<<eb, 256, 0, stream>>>(dst, et, counts, E);
    k_scan_part<<<nb, 256, 0, stream>>>(counts, partial, NS);
    k_scan_partials<<<1, 256, 0, stream>>>(partial, nb);
    k_scan_chunk<<<nb, 256, 0, stream>>>(counts, partial, offsets, cursor, NS);
    k_fill<<<eb, 256, 0, stream>>>(src, dst, et, cursor, esrc, eseg, E);

    k_ew<<<(E * HEADS + 255) / 256, 256, 0, stream>>>(esrc, eseg, si, sj, cpr, wbuf, N, E);

    k_node<<<(N + 3) / 4, 256, 0, stream>>>(xtb, offsets, counts, esrc, wbuf, imp, out, N);
}

// Round 6
// 354.101 us; speedup vs baseline: 1.6210x; 1.0972x over previous
//
#include <hip/hip_runtime.h>

#define IN_CH   128
#define D_OUT   128   // OUT_CH*HEADS
#define HEADS   4
#define N_TYPES 4
#define N_CONF  5
#define DCOLS   192   // 128 xt cols + 48 score cols (40 real + 8 pad)
#define SSTRIDE 24    // si/sj per-row stride: h*6+q (q<5 used)

typedef __attribute__((ext_vector_type(8))) short bf16x8;   // 8 bf16 (4 VGPRs)
typedef __attribute__((ext_vector_type(4))) float f32x4;

__device__ inline short bf16_rne(float f) {
    unsigned u = __float_as_uint(f);
    u += 0x7fff + ((u >> 16) & 1);
    return (short)(u >> 16);
}
// exact hi/lo split: f ~= hi + lo with ~2^-16 relative residual
__device__ inline void split_hl(float f, short& h, short& l) {
    unsigned u = __float_as_uint(f);
    h = (short)(u >> 16);
    float r = f - __uint_as_float(u & 0xffff0000u);   // exact
    l = (short)(__float_as_uint(r) >> 16);
}

// ---------------------------------------------------------------------------
// k_matt: M[t][k][col] = sum_{d'<32} W[t][k][32h+d'] * attv[q][h][fb*32+d']
//         col = fb*24 + h*6 + q  (q==5 -> 0 padding)
// ---------------------------------------------------------------------------
__global__ __launch_bounds__(256) void k_matt(const float* __restrict__ W,
                                              const float* __restrict__ attv,
                                              float* __restrict__ M) {
    const int g = blockIdx.x * 256 + threadIdx.x;   // 4*128*48
    if (g >= N_TYPES * 128 * 48) return;
    const int col = g % 48;
    const int k   = (g / 48) % 128;
    const int t   = g / (48 * 128);
    const int fb  = col / 24;
    const int rem = col % 24;
    const int h   = rem / 6;
    const int q   = rem % 6;
    float acc = 0.f;
    if (q < N_CONF) {
        const float* wr = W + ((size_t)t * 128 + k) * 128 + 32 * h;
        const float* ar = attv + ((size_t)q * HEADS + h) * 64 + fb * 32;
#pragma unroll
        for (int d = 0; d < 32; d++) acc += wr[d] * ar[d];
    }
    M[g] = acc;
}

// ---------------------------------------------------------------------------
// k_wprep: Wth/Wtl[t][dcol][k] = hi/lo bf16 of B'[t][k][dcol]
// ---------------------------------------------------------------------------
__global__ __launch_bounds__(256) void k_wprep(const float* __restrict__ W,
                                               const float* __restrict__ M,
                                               short* __restrict__ Wth,
                                               short* __restrict__ Wtl) {
    const int g = blockIdx.x * 256 + threadIdx.x;   // 4*128*192, dcol fastest
    if (g >= N_TYPES * 128 * DCOLS) return;
    const int dcol = g % DCOLS;
    const int k    = (g / DCOLS) % 128;
    const int t    = g / (DCOLS * 128);
    float v = 0.f;
    if (dcol < 128)      v = W[((size_t)t * 128 + k) * 128 + dcol];
    else if (dcol < 176) v = M[((size_t)t * 128 + k) * 48 + (dcol - 128)];
    short h, l; split_hl(v, h, l);
    const size_t o = ((size_t)t * DCOLS + dcol) * 128 + k;
    Wth[o] = h; Wtl[o] = l;
}

// ---------------------------------------------------------------------------
// k_linear: bf16 hi/lo MFMA GEMM, [64 nodes x 128 k] x [128 k x 192 cols].
// ---------------------------------------------------------------------------
__global__ __launch_bounds__(256) void k_linear(const float* __restrict__ x,
                                                const short* __restrict__ Wth,
                                                const short* __restrict__ Wtl,
                                                const float* __restrict__ bias,
                                                short* __restrict__ xtb,
                                                float* __restrict__ si,
                                                float* __restrict__ sj,
                                                float* __restrict__ out,
                                                int N) {
    __shared__ short Xh[64 * 136];          // row stride 136 shorts (272 B)
    __shared__ short Xl[64 * 136];

    const int tid   = threadIdx.x;
    const int nbase = blockIdx.x * 64;
    const int t     = blockIdx.y;

#pragma unroll
    for (int i = 0; i < 8; i++) {
        const int f   = tid + i * 256;       // 0..2047
        const int row = f >> 5;
        const int c4  = (f & 31) * 4;
        float4 v = make_float4(0.f, 0.f, 0.f, 0.f);
        const int ng = nbase + row;
        if (ng < N) v = *(const float4*)(x + (size_t)ng * IN_CH + c4);
        short4 h4, l4;
        split_hl(v.x, h4.x, l4.x);
        split_hl(v.y, h4.y, l4.y);
        split_hl(v.z, h4.z, l4.z);
        split_hl(v.w, h4.w, l4.w);
        *(short4*)(Xh + row * 136 + c4) = h4;
        *(short4*)(Xl + row * 136 + c4) = l4;
    }
    __syncthreads();

    const int w    = tid >> 6;
    const int lane = tid & 63;
    const int n16  = lane & 15;
    const int quad = lane >> 4;

    const size_t trow = (size_t)t * N;

#pragma unroll
    for (int tt = 0; tt < 3; tt++) {
        const int dcol = (w * 3 + tt) * 16 + n16;

        bf16x8 Bh[4], Bl[4];
        const size_t wof = ((size_t)t * DCOLS + dcol) * 128;
#pragma unroll
        for (int kc = 0; kc < 4; kc++) {
            Bh[kc] = *(const bf16x8*)(Wth + wof + kc * 32 + quad * 8);
            Bl[kc] = *(const bf16x8*)(Wtl + wof + kc * 32 + quad * 8);
        }

        f32x4 acc[4];
#pragma unroll
        for (int mt = 0; mt < 4; mt++) acc[mt] = (f32x4){0.f, 0.f, 0.f, 0.f};

#pragma unroll
        for (int kc = 0; kc < 4; kc++) {
            bf16x8 Ah[4], Al[4];
#pragma unroll
            for (int mt = 0; mt < 4; mt++) {
                const int r = (mt * 16 + n16) * 136 + kc * 32 + quad * 8;
                Ah[mt] = *(const bf16x8*)(Xh + r);
                Al[mt] = *(const bf16x8*)(Xl + r);
            }
#pragma unroll
            for (int mt = 0; mt < 4; mt++) {
                acc[mt] = __builtin_amdgcn_mfma_f32_16x16x32_bf16(Ah[mt], Bh[kc], acc[mt], 0, 0, 0);
                acc[mt] = __builtin_amdgcn_mfma_f32_16x16x32_bf16(Ah[mt], Bl[kc], acc[mt], 0, 0, 0);
                acc[mt] = __builtin_amdgcn_mfma_f32_16x16x32_bf16(Al[mt], Bh[kc], acc[mt], 0, 0, 0);
            }
        }

        if (dcol < 128) {
            const float bv = bias[dcol];
#pragma unroll
            for (int mt = 0; mt < 4; mt++)
#pragma unroll
                for (int r = 0; r < 4; r++) {
                    const int node = nbase + mt * 16 + quad * 4 + r;
                    if (node < N) {
                        const float v = acc[mt][r];
                        xtb[(trow + node) * (size_t)D_OUT + dcol] = bf16_rne(v);
                        if (t == 0) out[(size_t)node * D_OUT + dcol] = v + bv;
                    }
                }
        } else if (dcol < 176) {
            const int c   = dcol - 128;
            const int rem = c % 24;
            float* buf = (c < 24) ? si : sj;
#pragma unroll
            for (int mt = 0; mt < 4; mt++)
#pragma unroll
                for (int r = 0; r < 4; r++) {
                    const int node = nbase + mt * 16 + quad * 4 + r;
                    if (node < N)
                        buf[(trow + node) * SSTRIDE + rem] = acc[mt][r];
                }
        }
    }
}

// ---------------------------------------------------------------------------
// CSR build over segments seg = dst*4 + type
// ---------------------------------------------------------------------------
__global__ __launch_bounds__(256) void k_hist(const int* __restrict__ dst,
                                              const int* __restrict__ et,
                                              int* __restrict__ counts, int E) {
    const int e = blockIdx.x * 256 + threadIdx.x;
    if (e < E) atomicAdd(&counts[dst[e] * 4 + et[e]], 1);
}

__global__ __launch_bounds__(256) void k_scan_part(const int* __restrict__ counts,
                                                   int* __restrict__ partial, int NS) {
    __shared__ int s[256];
    const int b = blockIdx.x, t = threadIdx.x;
    const int base = b * 1024 + t * 4;
    int sum = 0;
#pragma unroll
    for (int i = 0; i < 4; i++) if (base + i < NS) sum += counts[base + i];
    s[t] = sum; __syncthreads();
    for (int off = 128; off > 0; off >>= 1) {
        if (t < off) s[t] += s[t + off];
        __syncthreads();
    }
    if (t == 0) partial[b] = s[0];
}

__global__ __launch_bounds__(256) void k_scan_partials(int* __restrict__ partial, int nb) {
    __shared__ int s[256];
    const int t = threadIdx.x;
    int v = (t < nb) ? partial[t] : 0;
    s[t] = v; __syncthreads();
    for (int off = 1; off < 256; off <<= 1) {
        int x = (t >= off) ? s[t - off] : 0;
        __syncthreads();
        s[t] += x;
        __syncthreads();
    }
    if (t < nb) partial[t] = s[t] - v;   // exclusive
}

__global__ __launch_bounds__(256) void k_scan_chunk(const int* __restrict__ counts,
                                                    const int* __restrict__ partial,
                                                    int* __restrict__ offsets,
                                                    int* __restrict__ cursor, int NS) {
    __shared__ int s[256];
    const int b = blockIdx.x, t = threadIdx.x;
    const int base = b * 1024 + t * 4;
    int v[4]; int sum = 0;
#pragma unroll
    for (int i = 0; i < 4; i++) { v[i] = (base + i < NS) ? counts[base + i] : 0; sum += v[i]; }
    s[t] = sum; __syncthreads();
    for (int off = 1; off < 256; off <<= 1) {
        int x = (t >= off) ? s[t - off] : 0;
        __syncthreads();
        s[t] += x;
        __syncthreads();
    }
    int run = partial[b] + s[t] - sum;
#pragma unroll
    for (int i = 0; i < 4; i++) {
        const int idx = base + i;
        if (idx < NS) { offsets[idx] = run; cursor[idx] = run; run += v[i]; }
    }
}

__global__ __launch_bounds__(256) void k_fill(const int* __restrict__ src,
                                              const int* __restrict__ dst,
                                              const int* __restrict__ et,
                                              int* __restrict__ cursor,
                                              int* __restrict__ esrc,
                                              int* __restrict__ eseg, int E) {
    const int e = blockIdx.x * 256 + threadIdx.x;
    if (e < E) {
        const int seg = dst[e] * 4 + et[e];
        const int pos = atomicAdd(&cursor[seg], 1);
        esrc[pos] = src[e];
        eseg[pos] = seg;
    }
}

// ---------------------------------------------------------------------------
// k_ew: one thread per (CSR pos, head); coalesced in & out.
// ---------------------------------------------------------------------------
__global__ __launch_bounds__(256) void k_ew(const int* __restrict__ esrc,
                                            const int* __restrict__ eseg,
                                            const float* __restrict__ si,
                                            const float* __restrict__ sj,
                                            const float* __restrict__ cprobs,
                                            float* __restrict__ wbuf,
                                            int N, int E) {
    __shared__ float pk_s[N_CONF];
    if (threadIdx.x == 0) {
        float m = cprobs[0];
        for (int k = 1; k < N_CONF; k++) m = fmaxf(m, cprobs[k]);
        float ex[N_CONF], s = 0.f;
        for (int k = 0; k < N_CONF; k++) { ex[k] = __expf(cprobs[k] - m); s += ex[k]; }
        for (int k = 0; k < N_CONF; k++) pk_s[k] = ex[k] / s;
    }
    __syncthreads();

    const int gid = blockIdx.x * 256 + threadIdx.x;
    const int p = gid >> 2;
    if (p >= E) return;
    const int h = gid & 3;

    const int seg = eseg[p];
    const int sn  = esrc[p];
    const int di  = seg >> 2;
    const int tt  = seg & 3;

    const float* ip = si + ((size_t)tt * N + di) * SSTRIDE + h * 6;
    const float* jp = sj + ((size_t)tt * N + sn) * SSTRIDE + h * 6;

    float alpha = 0.f;
#pragma unroll
    for (int q = 0; q < N_CONF; q++) {
        float s = ip[q] + jp[q];
        s = (s > 0.f) ? s : 0.2f * s;
        alpha += s * pk_s[q];
    }
    wbuf[(size_t)p * 4 + h] = __expf(alpha);
}

// ---------------------------------------------------------------------------
// k_node: one wave per dst node. esrc preloaded 64-edges-at-a-time with ONE
// coalesced load; per-edge src via __shfl (LDS crossbar) -> row-gather
// addresses have no global-load dependency -> deep MLP on the gathers.
// ---------------------------------------------------------------------------
__global__ __launch_bounds__(256) void k_node(const short* __restrict__ xtb,
                                              const int* __restrict__ offsets,
                                              const int* __restrict__ counts,
                                              const int* __restrict__ esrc,
                                              const float* __restrict__ wbuf,
                                              const float* __restrict__ imp,
                                              float* __restrict__ out,
                                              int N, int E) {
    __shared__ float imp_s[N_TYPES];
    if (threadIdx.x < N_TYPES) imp_s[threadIdx.x] = imp[threadIdx.x];
    __syncthreads();

    const int node = blockIdx.x * 4 + (threadIdx.x >> 6);
    if (node >= N) return;
    const int lane = threadIdx.x & 63;
    const int quad = lane >> 4;   // == head
    const size_t tstride = (size_t)N * D_OUT;

    const int o0 = offsets[node * 4];
    int c[N_TYPES];
#pragma unroll
    for (int t = 0; t < N_TYPES; t++) c[t] = counts[node * 4 + t];
    const int ndeg = c[0] + c[1] + c[2] + c[3];
    if (ndeg == 0) return;

    // chunked esrc preload state
    int chunk = -1;
    int sv = 0;

    float oacc0 = 0.f, oacc1 = 0.f;
    int k = 0;   // edge index relative to o0

#pragma unroll
    for (int t = 0; t < N_TYPES; t++) {
        const int cnt = c[t];
        if (cnt == 0) continue;
        float ax = 0.f, ay = 0.f, den = 0.f;
        const short* tbase = xtb + (size_t)t * tstride;
        for (int i = 0; i < cnt; i++, k++) {
            const int cc = k >> 6;
            if (cc != chunk) {                        // wave-uniform, rare
                chunk = cc;
                const int rel = cc * 64 + lane;
                sv = esrc[(rel < ndeg) ? (o0 + rel) : o0];   // 1 coalesced load
            }
            const int sn = __shfl(sv, k & 63);        // LDS crossbar, ~60cyc
            const float w = wbuf[(size_t)(o0 + k) * 4 + quad];  // linear addr
            const unsigned u = ((const unsigned*)(tbase + (size_t)sn * D_OUT))[lane];
            ax  += __uint_as_float(u << 16) * w;
            ay  += __uint_as_float(u & 0xffff0000u) * w;
            den += w;
        }
        const float f = imp_s[t] / den;
        oacc0 += ax * f;
        oacc1 += ay * f;
    }

    float2* op = (float2*)(out + (size_t)node * D_OUT) + lane;
    float2 ov = *op;
    ov.x += oacc0;
    ov.y += oacc1;
    *op = ov;
}

// ---------------------------------------------------------------------------
extern "C" void kernel_launch(void* const* d_in, const int* in_sizes, int n_in,
                              void* d_out, int out_size, void* d_ws, size_t ws_size,
                              hipStream_t stream) {
    const float* x    = (const float*)d_in[0];
    const int*   ei   = (const int*)d_in[1];
    const int*   et   = (const int*)d_in[2];
    const float* W    = (const float*)d_in[3];
    const float* attv = (const float*)d_in[4];
    const float* cpr  = (const float*)d_in[5];
    const float* imp  = (const float*)d_in[6];
    const float* bias = (const float*)d_in[7];

    const int N = in_sizes[0] / IN_CH;
    const int E = in_sizes[2];
    const int* src = ei;        // edge_index[0]
    const int* dst = ei + E;    // edge_index[1]
    const int NS = N * N_TYPES;

    char* ws = (char*)d_ws;
    float* si      = (float*)ws;  ws += (size_t)N_TYPES * N * SSTRIDE * sizeof(float);
    float* sj      = (float*)ws;  ws += (size_t)N_TYPES * N * SSTRIDE * sizeof(float);
    float* wbuf    = (float*)ws;  ws += (size_t)E * HEADS * sizeof(float);
    float* M       = (float*)ws;  ws += (size_t)N_TYPES * 128 * 48 * sizeof(float);
    short* Wth     = (short*)ws;  ws += (size_t)N_TYPES * DCOLS * 128 * sizeof(short);
    short* Wtl     = (short*)ws;  ws += (size_t)N_TYPES * DCOLS * 128 * sizeof(short);
    short* xtb     = (short*)ws;  ws += (size_t)N_TYPES * N * D_OUT * sizeof(short);
    int*   counts  = (int*)ws;    ws += (size_t)NS * sizeof(int);
    int*   offsets = (int*)ws;    ws += (size_t)NS * sizeof(int);
    int*   cursor  = (int*)ws;    ws += (size_t)NS * sizeof(int);
    int*   partial = (int*)ws;    ws += 256 * sizeof(int);
    int*   esrc    = (int*)ws;    ws += (size_t)E * sizeof(int);
    int*   eseg    = (int*)ws;    ws += (size_t)E * sizeof(int);
    float* out = (float*)d_out;

    hipMemsetAsync(counts, 0, (size_t)NS * sizeof(int), stream);

    k_matt<<<(N_TYPES * 128 * 48 + 255) / 256, 256, 0, stream>>>(W, attv, M);
    k_wprep<<<(N_TYPES * 128 * DCOLS + 255) / 256, 256, 0, stream>>>(W, M, Wth, Wtl);

    const int nblocks = (N + 63) / 64;
    k_linear<<<dim3(nblocks, N_TYPES), 256, 0, stream>>>(x, Wth, Wtl, bias, xtb, si, sj, out, N);

    const int eb = (E + 255) / 256;
    const int nb = (NS + 1023) / 1024;
    k_hist<<<eb, 256, 0, stream>>>(dst, et, counts, E);
    k_scan_part<<<nb, 256, 0, stream>>>(counts, partial, NS);
    k_scan_partials<<<1, 256, 0, stream>>>(partial, nb);
    k_scan_chunk<<<nb, 256, 0, stream>>>(counts, partial, offsets, cursor, NS);
    k_fill<<<eb, 256, 0, stream>>>(src, dst, et, cursor, esrc, eseg, E);

    k_ew<<<(E * HEADS + 255) / 256, 256, 0, stream>>>(esrc, eseg, si, sj, cpr, wbuf, N, E);

    k_node<<<(N + 3) / 4, 256, 0, stream>>>(xtb, offsets, counts, esrc, wbuf, imp, out, N, E);
}

// Round 7
// 331.645 us; speedup vs baseline: 1.7307x; 1.0677x over previous
//
#include <hip/hip_runtime.h>

#define IN_CH   128
#define D_OUT   128   // OUT_CH*HEADS
#define HEADS   4
#define N_TYPES 4
#define N_CONF  5
#define DCOLS   192   // 128 xt cols + 48 score cols (40 real + 8 pad)
#define SSTRIDE 24    // si/sj per-row stride: h*6+q (q<5 used)

typedef __attribute__((ext_vector_type(8))) short bf16x8;   // 8 bf16 (4 VGPRs)
typedef __attribute__((ext_vector_type(4))) float f32x4;

__device__ inline unsigned short bf16_rne(float f) {
    unsigned u = __float_as_uint(f);
    u += 0x7fff + ((u >> 16) & 1);
    return (unsigned short)(u >> 16);
}
// hi/lo split: f ~= hi + lo with ~2^-16 relative residual
__device__ inline void split_hl(float f, short& h, short& l) {
    unsigned u = __float_as_uint(f);
    h = (short)(u >> 16);
    float r = f - __uint_as_float(u & 0xffff0000u);   // exact
    l = (short)(__float_as_uint(r) >> 16);
}

// ---------------------------------------------------------------------------
// k_matt: M[t][k][col] = sum_{d'<32} W[t][k][32h+d'] * attv[q][h][fb*32+d']
//         col = fb*24 + h*6 + q  (q==5 -> 0 padding)
// ---------------------------------------------------------------------------
__global__ __launch_bounds__(256) void k_matt(const float* __restrict__ W,
                                              const float* __restrict__ attv,
                                              float* __restrict__ M) {
    const int g = blockIdx.x * 256 + threadIdx.x;   // 4*128*48
    if (g >= N_TYPES * 128 * 48) return;
    const int col = g % 48;
    const int k   = (g / 48) % 128;
    const int t   = g / (48 * 128);
    const int fb  = col / 24;
    const int rem = col % 24;
    const int h   = rem / 6;
    const int q   = rem % 6;
    float acc = 0.f;
    if (q < N_CONF) {
        const float* wr = W + ((size_t)t * 128 + k) * 128 + 32 * h;
        const float* ar = attv + ((size_t)q * HEADS + h) * 64 + fb * 32;
#pragma unroll
        for (int d = 0; d < 32; d++) acc += wr[d] * ar[d];
    }
    M[g] = acc;
}

// ---------------------------------------------------------------------------
// k_wprep: Wth/Wtl[t][dcol][k] = hi/lo bf16 of B'[t][k][dcol]
// ---------------------------------------------------------------------------
__global__ __launch_bounds__(256) void k_wprep(const float* __restrict__ W,
                                               const float* __restrict__ M,
                                               short* __restrict__ Wth,
                                               short* __restrict__ Wtl) {
    const int g = blockIdx.x * 256 + threadIdx.x;   // 4*128*192, dcol fastest
    if (g >= N_TYPES * 128 * DCOLS) return;
    const int dcol = g % DCOLS;
    const int k    = (g / DCOLS) % 128;
    const int t    = g / (DCOLS * 128);
    float v = 0.f;
    if (dcol < 128)      v = W[((size_t)t * 128 + k) * 128 + dcol];
    else if (dcol < 176) v = M[((size_t)t * 128 + k) * 48 + (dcol - 128)];
    short h, l; split_hl(v, h, l);
    const size_t o = ((size_t)t * DCOLS + dcol) * 128 + k;
    Wth[o] = h; Wtl[o] = l;
}

// ---------------------------------------------------------------------------
// k_linear: bf16 hi/lo MFMA GEMM, [64 nodes x 128 k] x [128 k x 192 cols].
// All 12 acc tiles in regs; LDS reused as swizzled stage; coalesced stores.
// ---------------------------------------------------------------------------
__global__ __launch_bounds__(256) void k_linear(const float* __restrict__ x,
                                                const short* __restrict__ Wth,
                                                const short* __restrict__ Wtl,
                                                short* __restrict__ xtb,
                                                float* __restrict__ si,
                                                float* __restrict__ sj,
                                                int N) {
    __shared__ __align__(16) char smem[34816];
    short* Xh = (short*)smem;             // 64*136 shorts
    short* Xl = (short*)(smem + 17408);   // 64*136 shorts

    const int tid   = threadIdx.x;
    const int nbase = blockIdx.x * 64;
    const int t     = blockIdx.y;

    // stage X tile -> hi/lo bf16
#pragma unroll
    for (int i = 0; i < 8; i++) {
        const int f   = tid + i * 256;       // 0..2047
        const int row = f >> 5;
        const int c4  = (f & 31) * 4;
        float4 v = make_float4(0.f, 0.f, 0.f, 0.f);
        const int ng = nbase + row;
        if (ng < N) v = *(const float4*)(x + (size_t)ng * IN_CH + c4);
        short4 h4, l4;
        split_hl(v.x, h4.x, l4.x);
        split_hl(v.y, h4.y, l4.y);
        split_hl(v.z, h4.z, l4.z);
        split_hl(v.w, h4.w, l4.w);
        *(short4*)(Xh + row * 136 + c4) = h4;
        *(short4*)(Xl + row * 136 + c4) = l4;
    }
    __syncthreads();

    const int w    = tid >> 6;
    const int lane = tid & 63;
    const int n16  = lane & 15;
    const int quad = lane >> 4;

    f32x4 acc[3][4];
#pragma unroll
    for (int tt = 0; tt < 3; tt++)
#pragma unroll
        for (int mt = 0; mt < 4; mt++) acc[tt][mt] = (f32x4){0.f, 0.f, 0.f, 0.f};

#pragma unroll
    for (int kc = 0; kc < 4; kc++) {
        bf16x8 Ah[4], Al[4];
#pragma unroll
        for (int mt = 0; mt < 4; mt++) {
            const int r = (mt * 16 + n16) * 136 + kc * 32 + quad * 8;
            Ah[mt] = *(const bf16x8*)(Xh + r);
            Al[mt] = *(const bf16x8*)(Xl + r);
        }
#pragma unroll
        for (int tt = 0; tt < 3; tt++) {
            const int dcol = (w * 3 + tt) * 16 + n16;
            const size_t off = ((size_t)t * DCOLS + dcol) * 128 + kc * 32 + quad * 8;
            const bf16x8 Bh = *(const bf16x8*)(Wth + off);
            const bf16x8 Bl = *(const bf16x8*)(Wtl + off);
#pragma unroll
            for (int mt = 0; mt < 4; mt++) {
                acc[tt][mt] = __builtin_amdgcn_mfma_f32_16x16x32_bf16(Ah[mt], Bh, acc[tt][mt], 0, 0, 0);
                acc[tt][mt] = __builtin_amdgcn_mfma_f32_16x16x32_bf16(Ah[mt], Bl, acc[tt][mt], 0, 0, 0);
                acc[tt][mt] = __builtin_amdgcn_mfma_f32_16x16x32_bf16(Al[mt], Bh, acc[tt][mt], 0, 0, 0);
            }
        }
    }

    // -------- stage epilogue through LDS (reuse smem) --------
    __syncthreads();
    unsigned short* SB = (unsigned short*)smem;     // [64][128], 16B-block swizzled
    float*          SS = (float*)(smem + 32768);    // wait: SB ends at 16384
    SS = (float*)(smem + 16384);                    // [64][48]

#pragma unroll
    for (int tt = 0; tt < 3; tt++) {
        const int dcol = (w * 3 + tt) * 16 + n16;
        if (dcol < 128) {
            const int blk = dcol >> 3;
#pragma unroll
            for (int mt = 0; mt < 4; mt++)
#pragma unroll
                for (int r = 0; r < 4; r++) {
                    const int nl = mt * 16 + quad * 4 + r;
                    SB[nl * 128 + (((blk ^ (nl & 15)) << 3) | (dcol & 7))] =
                        bf16_rne(acc[tt][mt][r]);
                }
        } else if (dcol < 176) {
            const int c = dcol - 128;   // 0..47: [si 0..23 | sj 0..23]
#pragma unroll
            for (int mt = 0; mt < 4; mt++)
#pragma unroll
                for (int r = 0; r < 4; r++) {
                    const int nl = mt * 16 + quad * 4 + r;
                    SS[nl * 48 + c] = acc[tt][mt][r];
                }
        }
    }
    __syncthreads();

    const size_t trow = (size_t)t * N;
    // xtb: 64 rows x 16 blocks of 16B, coalesced dwordx4 stores
#pragma unroll
    for (int it = 0; it < 4; it++) {
        const int task = tid + it * 256;        // 0..1023
        const int r    = task >> 4;
        const int blk  = task & 15;
        if (nbase + r < N) {
            const uint4 v = *(const uint4*)(SB + r * 128 + ((blk ^ (r & 15)) << 3));
            *(uint4*)(xtb + (trow + nbase + r) * (size_t)D_OUT + (blk << 3)) = v;
        }
    }
    // scores: 64 rows x 12 float4 pieces (6 si + 6 sj)
#pragma unroll
    for (int it = 0; it < 3; it++) {
        const int task = tid + it * 256;        // 0..767
        const int r    = task / 12;
        const int p    = task % 12;
        if (nbase + r < N) {
            const float4 v = *(const float4*)(SS + r * 48 + p * 4);
            float* dp = (p < 6) ? (si + (trow + nbase + r) * SSTRIDE + p * 4)
                                : (sj + (trow + nbase + r) * SSTRIDE + (p - 6) * 4);
            *(float4*)dp = v;
        }
    }
}

// ---------------------------------------------------------------------------
// CSR build over segments seg = dst*4 + type
// ---------------------------------------------------------------------------
__global__ __launch_bounds__(256) void k_hist(const int* __restrict__ dst,
                                              const int* __restrict__ et,
                                              int* __restrict__ counts, int E) {
    const int e = blockIdx.x * 256 + threadIdx.x;
    if (e < E) atomicAdd(&counts[dst[e] * 4 + et[e]], 1);
}

__global__ __launch_bounds__(256) void k_scan_part(const int* __restrict__ counts,
                                                   int* __restrict__ partial, int NS) {
    __shared__ int s[256];
    const int b = blockIdx.x, t = threadIdx.x;
    const int base = b * 1024 + t * 4;
    int sum = 0;
#pragma unroll
    for (int i = 0; i < 4; i++) if (base + i < NS) sum += counts[base + i];
    s[t] = sum; __syncthreads();
    for (int off = 128; off > 0; off >>= 1) {
        if (t < off) s[t] += s[t + off];
        __syncthreads();
    }
    if (t == 0) partial[b] = s[0];
}

__global__ __launch_bounds__(256) void k_scan_partials(int* __restrict__ partial, int nb) {
    __shared__ int s[256];
    const int t = threadIdx.x;
    int v = (t < nb) ? partial[t] : 0;
    s[t] = v; __syncthreads();
    for (int off = 1; off < 256; off <<= 1) {
        int x = (t >= off) ? s[t - off] : 0;
        __syncthreads();
        s[t] += x;
        __syncthreads();
    }
    if (t < nb) partial[t] = s[t] - v;   // exclusive
}

__global__ __launch_bounds__(256) void k_scan_chunk(const int* __restrict__ counts,
                                                    const int* __restrict__ partial,
                                                    int* __restrict__ offsets,
                                                    int* __restrict__ cursor, int NS) {
    __shared__ int s[256];
    const int b = blockIdx.x, t = threadIdx.x;
    const int base = b * 1024 + t * 4;
    int v[4]; int sum = 0;
#pragma unroll
    for (int i = 0; i < 4; i++) { v[i] = (base + i < NS) ? counts[base + i] : 0; sum += v[i]; }
    s[t] = sum; __syncthreads();
    for (int off = 1; off < 256; off <<= 1) {
        int x = (t >= off) ? s[t - off] : 0;
        __syncthreads();
        s[t] += x;
        __syncthreads();
    }
    int run = partial[b] + s[t] - sum;
#pragma unroll
    for (int i = 0; i < 4; i++) {
        const int idx = base + i;
        if (idx < NS) { offsets[idx] = run; cursor[idx] = run; run += v[i]; }
    }
}

__global__ __launch_bounds__(256) void k_fill(const int* __restrict__ src,
                                              const int* __restrict__ dst,
                                              const int* __restrict__ et,
                                              int* __restrict__ cursor,
                                              int* __restrict__ esrc,
                                              int* __restrict__ eseg, int E) {
    const int e = blockIdx.x * 256 + threadIdx.x;
    if (e < E) {
        const int seg = dst[e] * 4 + et[e];
        const int pos = atomicAdd(&cursor[seg], 1);
        esrc[pos] = src[e];
        eseg[pos] = seg;
    }
}

// ---------------------------------------------------------------------------
// k_ew: one thread per (CSR pos, head); coalesced in & out.
// ---------------------------------------------------------------------------
__global__ __launch_bounds__(256) void k_ew(const int* __restrict__ esrc,
                                            const int* __restrict__ eseg,
                                            const float* __restrict__ si,
                                            const float* __restrict__ sj,
                                            const float* __restrict__ cprobs,
                                            float* __restrict__ wbuf,
                                            int N, int E) {
    __shared__ float pk_s[N_CONF];
    if (threadIdx.x == 0) {
        float m = cprobs[0];
        for (int k = 1; k < N_CONF; k++) m = fmaxf(m, cprobs[k]);
        float ex[N_CONF], s = 0.f;
        for (int k = 0; k < N_CONF; k++) { ex[k] = __expf(cprobs[k] - m); s += ex[k]; }
        for (int k = 0; k < N_CONF; k++) pk_s[k] = ex[k] / s;
    }
    __syncthreads();

    const int gid = blockIdx.x * 256 + threadIdx.x;
    const int p = gid >> 2;
    if (p >= E) return;
    const int h = gid & 3;

    const int seg = eseg[p];
    const int sn  = esrc[p];
    const int di  = seg >> 2;
    const int tt  = seg & 3;

    const float* ip = si + ((size_t)tt * N + di) * SSTRIDE + h * 6;
    const float* jp = sj + ((size_t)tt * N + sn) * SSTRIDE + h * 6;

    float alpha = 0.f;
#pragma unroll
    for (int q = 0; q < N_CONF; q++) {
        float s = ip[q] + jp[q];
        s = (s > 0.f) ? s : 0.2f * s;
        alpha += s * pk_s[q];
    }
    wbuf[(size_t)p * 4 + h] = __expf(alpha);
}

// ---------------------------------------------------------------------------
// k_node: one wave per dst node; chunked esrc preload + __shfl distribution;
// epilogue: out = fp32(xtb[0][node]) + bias + messages (pure coalesced store).
// ---------------------------------------------------------------------------
__global__ __launch_bounds__(256) void k_node(const short* __restrict__ xtb,
                                              const int* __restrict__ offsets,
                                              const int* __restrict__ counts,
                                              const int* __restrict__ esrc,
                                              const float* __restrict__ wbuf,
                                              const float* __restrict__ imp,
                                              const float* __restrict__ bias,
                                              float* __restrict__ out,
                                              int N) {
    __shared__ float imp_s[N_TYPES];
    if (threadIdx.x < N_TYPES) imp_s[threadIdx.x] = imp[threadIdx.x];
    __syncthreads();

    const int node = blockIdx.x * 4 + (threadIdx.x >> 6);
    if (node >= N) return;
    const int lane = threadIdx.x & 63;
    const int quad = lane >> 4;   // == head
    const size_t tstride = (size_t)N * D_OUT;

    const int o0 = offsets[node * 4];
    int c[N_TYPES];
#pragma unroll
    for (int t = 0; t < N_TYPES; t++) c[t] = counts[node * 4 + t];
    const int ndeg = c[0] + c[1] + c[2] + c[3];

    int chunk = -1;
    int sv = 0;
    float oacc0 = 0.f, oacc1 = 0.f;
    int k = 0;

#pragma unroll
    for (int t = 0; t < N_TYPES; t++) {
        const int cnt = c[t];
        if (cnt == 0) continue;
        float ax = 0.f, ay = 0.f, den = 0.f;
        const short* tbase = xtb + (size_t)t * tstride;
        for (int i = 0; i < cnt; i++, k++) {
            const int cc = k >> 6;
            if (cc != chunk) {                        // wave-uniform, rare
                chunk = cc;
                const int rel = cc * 64 + lane;
                sv = esrc[(rel < ndeg) ? (o0 + rel) : o0];   // 1 coalesced load
            }
            const int sn = __shfl(sv, k & 63);
            const float w = wbuf[(size_t)(o0 + k) * 4 + quad];
            const unsigned u = ((const unsigned*)(tbase + (size_t)sn * D_OUT))[lane];
            ax  += __uint_as_float(u << 16) * w;
            ay  += __uint_as_float(u & 0xffff0000u) * w;
            den += w;
        }
        const float f = imp_s[t] / den;
        oacc0 += ax * f;
        oacc1 += ay * f;
    }

    // self-loop (type 0 transform of own features) + bias, pure store
    const unsigned u0 = ((const unsigned*)(xtb + (size_t)node * D_OUT))[lane];
    const float2 bv = ((const float2*)bias)[lane];
    float2 ov;
    ov.x = __uint_as_float(u0 << 16)          + bv.x + oacc0;
    ov.y = __uint_as_float(u0 & 0xffff0000u)  + bv.y + oacc1;
    ((float2*)(out + (size_t)node * D_OUT))[lane] = ov;
}

// ---------------------------------------------------------------------------
extern "C" void kernel_launch(void* const* d_in, const int* in_sizes, int n_in,
                              void* d_out, int out_size, void* d_ws, size_t ws_size,
                              hipStream_t stream) {
    const float* x    = (const float*)d_in[0];
    const int*   ei   = (const int*)d_in[1];
    const int*   et   = (const int*)d_in[2];
    const float* W    = (const float*)d_in[3];
    const float* attv = (const float*)d_in[4];
    const float* cpr  = (const float*)d_in[5];
    const float* imp  = (const float*)d_in[6];
    const float* bias = (const float*)d_in[7];

    const int N = in_sizes[0] / IN_CH;
    const int E = in_sizes[2];
    const int* src = ei;        // edge_index[0]
    const int* dst = ei + E;    // edge_index[1]
    const int NS = N * N_TYPES;

    char* ws = (char*)d_ws;
    float* si      = (float*)ws;  ws += (size_t)N_TYPES * N * SSTRIDE * sizeof(float);
    float* sj      = (float*)ws;  ws += (size_t)N_TYPES * N * SSTRIDE * sizeof(float);
    float* wbuf    = (float*)ws;  ws += (size_t)E * HEADS * sizeof(float);
    float* M       = (float*)ws;  ws += (size_t)N_TYPES * 128 * 48 * sizeof(float);
    short* Wth     = (short*)ws;  ws += (size_t)N_TYPES * DCOLS * 128 * sizeof(short);
    short* Wtl     = (short*)ws;  ws += (size_t)N_TYPES * DCOLS * 128 * sizeof(short);
    short* xtb     = (short*)ws;  ws += (size_t)N_TYPES * N * D_OUT * sizeof(short);
    int*   counts  = (int*)ws;    ws += (size_t)NS * sizeof(int);
    int*   offsets = (int*)ws;    ws += (size_t)NS * sizeof(int);
    int*   cursor  = (int*)ws;    ws += (size_t)NS * sizeof(int);
    int*   partial = (int*)ws;    ws += 256 * sizeof(int);
    int*   esrc    = (int*)ws;    ws += (size_t)E * sizeof(int);
    int*   eseg    = (int*)ws;    ws += (size_t)E * sizeof(int);
    float* out = (float*)d_out;

    hipMemsetAsync(counts, 0, (size_t)NS * sizeof(int), stream);

    k_matt<<<(N_TYPES * 128 * 48 + 255) / 256, 256, 0, stream>>>(W, attv, M);
    k_wprep<<<(N_TYPES * 128 * DCOLS + 255) / 256, 256, 0, stream>>>(W, M, Wth, Wtl);

    const int nblocks = (N + 63) / 64;
    k_linear<<<dim3(nblocks, N_TYPES), 256, 0, stream>>>(x, Wth, Wtl, xtb, si, sj, N);

    const int eb = (E + 255) / 256;
    const int nb = (NS + 1023) / 1024;
    k_hist<<<eb, 256, 0, stream>>>(dst, et, counts, E);
    k_scan_part<<<nb, 256, 0, stream>>>(counts, partial, NS);
    k_scan_partials<<<1, 256, 0, stream>>>(partial, nb);
    k_scan_chunk<<<nb, 256, 0, stream>>>(counts, partial, offsets, cursor, NS);
    k_fill<<<eb, 256, 0, stream>>>(src, dst, et, cursor, esrc, eseg, E);

    k_ew<<<(E * HEADS + 255) / 256, 256, 0, stream>>>(esrc, eseg, si, sj, cpr, wbuf, N, E);

    k_node<<<(N + 3) / 4, 256, 0, stream>>>(xtb, offsets, counts, esrc, wbuf, imp, bias, out, N);
}